// Round 11
// baseline (27.556 us; speedup 1.0000x reference)
//
#include <hip/hip_runtime.h>
#include <hip/hip_bf16.h>
#include <math.h>

#define C 128
#define RANK 64
#define NB 8192
#define BATCH 2
#define NCHUNK 128                 // 64-row chunks per batch

typedef float f32x4 __attribute__((ext_vector_type(4)));
typedef short bf16x8 __attribute__((ext_vector_type(8)));
typedef unsigned short u16x4 __attribute__((ext_vector_type(4)));

__device__ __forceinline__ unsigned short f2b(float f) {
  __hip_bfloat16 h = __float2bfloat16(f);
  return *reinterpret_cast<unsigned short*>(&h);
}
__device__ __forceinline__ float b2f(unsigned short h) {
  union { unsigned u; float f; } v; v.u = ((unsigned)h) << 16;
  return v.f;
}
// cubic-tanh GELU; rcp approx instead of exact divide
__device__ __forceinline__ float gelu_fast(float y) {
  float u = y * (1.0f + 0.044715f * y * y);
  float e = __expf(1.5957691216057308f * u);     // e^{2*0.7978845608*u}
  float t = 1.0f - 2.0f * __builtin_amdgcn_rcpf(e + 1.0f);
  return 0.5f * y * (1.0f + t);
}
#define MFMA(a, b, c) __builtin_amdgcn_mfma_f32_16x16x32_bf16(a, b, c, 0, 0, 0)

// ---------------------------------------------------------------------------
// k_gram: EXACTLY 256 blocks (1/CU). Each: 64-row Gram partial via MFMA
// (8 waves), partG stored bf16 in MFMA C-fragment flat order
// fidx(w,tj,l,q) = (w*8+tj)*256 + l*4 + q  holding
// G[ci=w*16+(l>>4)*4+q][cj=tj*16+(l&15)]. Also writes xbf: row-major bf16
// copy of x (same f2b values) for k_main's A-fragments. Blocks 0-11
// additionally pack W_w / phi_w into bf16 MFMA B-fragment order:
//   o = ((nt*KT+kt)*64 + lane)*8 + j  holds
//   B[k = kt*32 + (lane>>4)*8 + j][n = nt*16 + (lane&15)].
// ---------------------------------------------------------------------------
__global__ __launch_bounds__(512) void k_gram(
    const float* __restrict__ x, unsigned short* __restrict__ partG,
    float* __restrict__ partS, unsigned short* __restrict__ xbf,
    unsigned short* __restrict__ wtf, unsigned short* __restrict__ pwf,
    const float* __restrict__ W_w, const float* __restrict__ phi_w) {
  __shared__ short xsT[C * 76];     // [c][n] bf16, stride 76
  __shared__ float csp[16][C];      // colsum partials (16 row-groups)
  const int blk = blockIdx.x;
  const int tid = threadIdx.x;
  const int b = blk >> 7, chunk = blk & 127;
  const size_t rowbase = (size_t)(b * NB + chunk * 64);
  const float* xb = x + rowbase * C;
  {
    // thread: c-quad = (tid&31)*4, rows n = it*16 + (tid>>5), it=0..3
    const int cq = (tid & 31) * 4, rg = tid >> 5;
    float cs0 = 0.f, cs1 = 0.f, cs2 = 0.f, cs3 = 0.f;
#pragma unroll
    for (int it = 0; it < 4; ++it) {
      int n = it * 16 + rg;
      f32x4 v = *(const f32x4*)(xb + (size_t)n * C + cq);
      cs0 += v[0]; cs1 += v[1]; cs2 += v[2]; cs3 += v[3];
      u16x4 pv;
#pragma unroll
      for (int q = 0; q < 4; ++q) pv[q] = f2b(v[q]);
      *(u16x4*)(xbf + (rowbase + n) * C + cq) = pv;   // row-major bf16 copy
      xsT[(cq + 0) * 76 + n] = (short)pv[0];
      xsT[(cq + 1) * 76 + n] = (short)pv[1];
      xsT[(cq + 2) * 76 + n] = (short)pv[2];
      xsT[(cq + 3) * 76 + n] = (short)pv[3];
    }
    csp[rg][cq + 0] = cs0;
    csp[rg][cq + 1] = cs1;
    csp[rg][cq + 2] = cs2;
    csp[rg][cq + 3] = cs3;
  }
  __syncthreads();
  const int l = tid & 63, w = tid >> 6;       // 8 waves, wave = 16-row G tile
  const int lr = l & 15, lq = l >> 4;
  f32x4 acc[8];
#pragma unroll
  for (int tj = 0; tj < 8; ++tj) acc[tj] = (f32x4)(0.f);
  bf16x8 af[2];
#pragma unroll
  for (int kk = 0; kk < 2; ++kk)
    af[kk] = *(const bf16x8*)(&xsT[(w * 16 + lr) * 76 + kk * 32 + lq * 8]);
#pragma unroll
  for (int tj = 0; tj < 8; ++tj)
#pragma unroll
    for (int kk = 0; kk < 2; ++kk) {
      bf16x8 bfr = *(const bf16x8*)(&xsT[(tj * 16 + lr) * 76 + kk * 32 + lq * 8]);
      acc[tj] = MFMA(af[kk], bfr, acc[tj]);
    }
  // store in fragment order: lane-contiguous u16x4 (8B) per tj
  unsigned short* dst = partG + (size_t)blk * (C * C);
#pragma unroll
  for (int tj = 0; tj < 8; ++tj) {
    u16x4 pv;
#pragma unroll
    for (int q = 0; q < 4; ++q) pv[q] = f2b(acc[tj][q]);
    *(u16x4*)(dst + (w * 8 + tj) * 256 + l * 4) = pv;
  }
  if (tid < C) {
    float s = 0.f;
#pragma unroll
    for (int g = 0; g < 16; ++g) s += csp[g][tid];
    partS[blk * C + tid] = s;
  }
  // ---- weight packing folded into blocks 0-11 (no extra block-wave) ----
  if (blk < 8) {        // wtf: 16384 elems, 2048/block
    int o0 = blk * 2048 + tid * 4;
    u16x4 v;
#pragma unroll
    for (int q = 0; q < 4; ++q) {
      int o = o0 + q;
      int j = o & 7, lane = (o >> 3) & 63, kt = (o >> 9) & 3, nt = o >> 11;
      int n = nt * 16 + (lane & 15);
      int k = kt * 32 + ((lane >> 4) << 3) + j;
      v[q] = f2b(W_w[k * C + n]);
    }
    *(u16x4*)(wtf + o0) = v;
  } else if (blk < 12) { // pwf: 8192 elems, 2048/block
    int o0 = (blk - 8) * 2048 + tid * 4;
    u16x4 v;
#pragma unroll
    for (int q = 0; q < 4; ++q) {
      int o = o0 + q;
      int j = o & 7, lane = (o >> 3) & 63, kt = (o >> 9) & 3, nt = o >> 11;
      int r = nt * 16 + (lane & 15);
      int c = kt * 32 + ((lane >> 4) << 3) + j;
      v[q] = f2b(phi_w[c * RANK + r]);
    }
    *(u16x4*)(pwf + o0) = v;
  }
}

// ---------------------------------------------------------------------------
// k_reduce: EXACTLY 256 blocks. b = e>>7, i0 = (e&127)*128; 256 thr =
// (chg 8) x (ig 32); each thread sums 16 chunks of u16x4; LDS tree.
// Blocks 0-1 additionally reduce partS for batch e (folded, no extra wave).
// ---------------------------------------------------------------------------
__global__ __launch_bounds__(256) void k_reduce(
    const unsigned short* __restrict__ partG, const float* __restrict__ partS,
    float* __restrict__ gsumG, float* __restrict__ gsumS) {
  __shared__ f32x4 red[256];
  __shared__ float s2[2][C];
  const int e = blockIdx.x, tid = threadIdx.x;
  const int b = e >> 7, i0 = (e & 127) * 128;
  const int chg = tid >> 5, ig = tid & 31;
  f32x4 a = (f32x4)(0.f);
  const unsigned short* base =
      partG + (size_t)(b * NCHUNK + chg * 16) * (C * C) + i0 + ig * 4;
#pragma unroll
  for (int cc = 0; cc < 16; ++cc) {
    u16x4 v = *(const u16x4*)(base + (size_t)cc * (C * C));
#pragma unroll
    for (int q = 0; q < 4; ++q) a[q] += b2f(v[q]);
  }
  red[tid] = a;
  if (e < 2) {  // partS reduce for batch e
    const int c = tid & 127, half = tid >> 7;
    const float* p = partS + (size_t)(e * NCHUNK + half * 64) * C + c;
    float s = 0.f;
#pragma unroll
    for (int cc = 0; cc < 64; ++cc) s += p[(size_t)cc * C];
    s2[half][c] = s;
  }
  __syncthreads();
  if (tid < 32) {
    f32x4 s = red[tid];
#pragma unroll
    for (int g = 1; g < 8; ++g) {
      f32x4 r = red[g * 32 + tid];
#pragma unroll
      for (int q = 0; q < 4; ++q) s[q] += r[q];
    }
    *(f32x4*)(&gsumG[b * (C * C) + i0 + tid * 4]) = s;
  }
  if (e < 2 && tid < C) gsumS[e * C + tid] = s2[0][tid] + s2[1][tid];
}

// ---------------------------------------------------------------------------
// k_integral: integ[b][r][c] = (sum_k psiw[k][r*C+c]*G[b][k][c]
//                               + psib[r*C+c]*S[b][c]) / NB -> itf (bf16 frag)
// grid (r=64, ch=4), 256 threads = kg(8) x c32(32); both batches per thread.
// G is in fragment-flat order: 4 consecutive k (one q-group) = one f32x4.
//   fidx(k4,c) = ((k4>>2)*8 + (c>>4))*256 + ((k4&3)*16 + (c&15))*4
// ---------------------------------------------------------------------------
__global__ __launch_bounds__(256) void k_integral(
    const float* __restrict__ psi_w, const float* __restrict__ psi_b,
    const float* __restrict__ gsumG, const float* __restrict__ gsumS,
    unsigned short* __restrict__ itf) {
  __shared__ float red[2][8][32];
  const int r = blockIdx.x, ch = blockIdx.y;
  const int tid = threadIdx.x, kg = tid >> 5, c32 = tid & 31;
  const int c = ch * 32 + c32;
  const int tj = c >> 4, lr = c & 15;
  const float* psW = psi_w + (size_t)r * C + c;
  float a0 = 0.f, a1 = 0.f;
#pragma unroll
  for (int i = 0; i < 4; ++i) {
    int k4 = kg * 4 + i;               // k = k4*4 + q, q=0..3
    int fidx = ((k4 >> 2) * 8 + tj) * 256 + ((k4 & 3) * 16 + lr) * 4;
    f32x4 g0 = *(const f32x4*)(gsumG + fidx);
    f32x4 g1 = *(const f32x4*)(gsumG + C * C + fidx);
#pragma unroll
    for (int q = 0; q < 4; ++q) {
      float pw = psW[(size_t)(k4 * 4 + q) * (RANK * C)];
      a0 += pw * g0[q];
      a1 += pw * g1[q];
    }
  }
  red[0][kg][c32] = a0;
  red[1][kg][c32] = a1;
  __syncthreads();
  if (tid < 64) {
    int b = tid >> 5, cc = tid & 31;
    float s = 0.f;
#pragma unroll
    for (int g = 0; g < 8; ++g) s += red[b][g][cc];
    int cg = ch * 32 + cc;
    s += psi_b[r * C + cg] * gsumS[b * C + cg];
    s *= (1.0f / NB);
    int nt = cg >> 4, kt = r >> 5;
    int lane = ((r >> 3) & 3) * 16 + (cg & 15), j = r & 7;
    itf[(size_t)(((b * 8 + nt) * 2 + kt) * 64 + lane) * 8 + j] = f2b(s);
  }
}

// ---------------------------------------------------------------------------
// k_main: 32 rows/block, 256 threads (4 waves = 4 col-tiles), MFMA fused.
// A-fragments loaded as bf16x8 DIRECTLY from xbf (row-major bf16 x written
// by k_gram) — no f32 re-read, no cvt. Single barrier (phi exchange).
//   T1 phi = x*phi_w + phi_b ; T2 acc = x*W_w + W_b ; T3 acc += phi*integ
//   out = gelu_fast(acc)
// ---------------------------------------------------------------------------
__global__ __launch_bounds__(256, 2) void k_main(
    const unsigned short* __restrict__ xbf, const float* __restrict__ W_b,
    const float* __restrict__ phi_b, const unsigned short* __restrict__ wtf,
    const unsigned short* __restrict__ pwf, const unsigned short* __restrict__ itf,
    float* __restrict__ out) {
  __shared__ short phT[32 * 72];
  const int tid = threadIdx.x, l = tid & 63, wn = tid >> 6;
  const int row0 = blockIdx.x * 32;
  const int b = blockIdx.x >> 8;
  const int lr = l & 15, lq = l >> 4;
  bf16x8 wb[2][4], pw[4], itb[2][2];
  const bf16x8* WF = (const bf16x8*)wtf;
  const bf16x8* PF = (const bf16x8*)pwf;
  const bf16x8* IF = (const bf16x8*)itf;
#pragma unroll
  for (int j = 0; j < 2; ++j)
#pragma unroll
    for (int kt = 0; kt < 4; ++kt)
      wb[j][kt] = WF[((wn * 2 + j) * 4 + kt) * 64 + l];
#pragma unroll
  for (int kt = 0; kt < 4; ++kt) pw[kt] = PF[(wn * 4 + kt) * 64 + l];
#pragma unroll
  for (int j = 0; j < 2; ++j)
#pragma unroll
    for (int kt = 0; kt < 2; ++kt)
      itb[j][kt] = IF[((b * 8 + wn * 2 + j) * 2 + kt) * 64 + l];
  bf16x8 afr[2][4];
#pragma unroll
  for (int h = 0; h < 2; ++h) {
    const unsigned short* xr = xbf + (size_t)(row0 + h * 16 + lr) * C + lq * 8;
#pragma unroll
    for (int kt = 0; kt < 4; ++kt)
      afr[h][kt] = *(const bf16x8*)(xr + kt * 32);
  }
  float wb0 = W_b[wn * 32 + lr], wb1 = W_b[wn * 32 + 16 + lr];
  float pb0 = phi_b[wn * 16 + lr];
  f32x4 acc[2][2], pacc[2];
#pragma unroll
  for (int i = 0; i < 2; ++i) {
    acc[i][0] = (f32x4)(wb0);
    acc[i][1] = (f32x4)(wb1);
    pacc[i] = (f32x4)(pb0);
  }
#pragma unroll
  for (int kt = 0; kt < 4; ++kt) {
    pacc[0] = MFMA(afr[0][kt], pw[kt], pacc[0]);
    pacc[1] = MFMA(afr[1][kt], pw[kt], pacc[1]);
    acc[0][0] = MFMA(afr[0][kt], wb[0][kt], acc[0][0]);
    acc[0][1] = MFMA(afr[0][kt], wb[1][kt], acc[0][1]);
    acc[1][0] = MFMA(afr[1][kt], wb[0][kt], acc[1][0]);
    acc[1][1] = MFMA(afr[1][kt], wb[1][kt], acc[1][1]);
  }
#pragma unroll
  for (int i = 0; i < 2; ++i)
#pragma unroll
    for (int q = 0; q < 4; ++q) {
      int row = i * 16 + lq * 4 + q;
      phT[row * 72 + wn * 16 + lr] = (short)f2b(pacc[i][q]);
    }
  __syncthreads();
#pragma unroll
  for (int kt = 0; kt < 2; ++kt) {
    bf16x8 p0 = *(const bf16x8*)(&phT[lr * 72 + kt * 32 + lq * 8]);
    bf16x8 p1 = *(const bf16x8*)(&phT[(16 + lr) * 72 + kt * 32 + lq * 8]);
    acc[0][0] = MFMA(p0, itb[0][kt], acc[0][0]);
    acc[0][1] = MFMA(p0, itb[1][kt], acc[0][1]);
    acc[1][0] = MFMA(p1, itb[0][kt], acc[1][0]);
    acc[1][1] = MFMA(p1, itb[1][kt], acc[1][1]);
  }
#pragma unroll
  for (int i = 0; i < 2; ++i)
#pragma unroll
    for (int j = 0; j < 2; ++j)
#pragma unroll
      for (int q = 0; q < 4; ++q) {
        int row = row0 + i * 16 + lq * 4 + q;
        int col = wn * 32 + j * 16 + lr;
        out[(size_t)row * C + col] = gelu_fast(acc[i][j][q]);
      }
}

extern "C" void kernel_launch(void* const* d_in, const int* in_sizes, int n_in,
                              void* d_out, int out_size, void* d_ws, size_t ws_size,
                              hipStream_t stream) {
  const float* x     = (const float*)d_in[0];
  const float* W_w   = (const float*)d_in[1];
  const float* W_b   = (const float*)d_in[2];
  const float* phi_w = (const float*)d_in[3];
  const float* phi_b = (const float*)d_in[4];
  const float* psi_w = (const float*)d_in[5];
  const float* psi_b = (const float*)d_in[6];
  float* out = (float*)d_out;

  // ws: partG[256*16384 bf16] | partS[256*128 f32] | gsumG[2*16384 f32]
  //     | gsumS[256 f32] | wtf[16384 bf16] | pwf[8192 bf16] | itf[16384 bf16]
  //     | xbf[2*8192*128 bf16]
  unsigned short* partG = (unsigned short*)d_ws;
  float* partS = (float*)(partG + (size_t)BATCH * NCHUNK * C * C);
  float* gsumG = partS + (size_t)BATCH * NCHUNK * C;
  float* gsumS = gsumG + BATCH * C * C;
  unsigned short* wtf = (unsigned short*)(gsumS + BATCH * C);
  unsigned short* pwf = wtf + 16384;
  unsigned short* itf = pwf + 8192;
  unsigned short* xbf = itf + 16384;

  k_gram<<<BATCH * NCHUNK, 512, 0, stream>>>(x, partG, partS, xbf, wtf, pwf,
                                             W_w, phi_w);
  k_reduce<<<BATCH * NCHUNK, 256, 0, stream>>>(partG, partS, gsumG, gsumS);
  k_integral<<<dim3(RANK, 4), 256, 0, stream>>>(psi_w, psi_b, gsumG, gsumS,
                                                itf);
  k_main<<<(BATCH * NB) / 32, 256, 0, stream>>>(xbf, W_b, phi_b, wtf, pwf, itf,
                                                out);
}

// Round 12
// 27.387 us; speedup vs baseline: 1.0062x; 1.0062x over previous
//
#include <hip/hip_runtime.h>
#include <hip/hip_bf16.h>
#include <math.h>

#define C 128
#define RANK 64
#define NB 8192
#define BATCH 2
#define NCHUNK 128                 // 64-row chunks per batch

typedef float f32x4 __attribute__((ext_vector_type(4)));
typedef short bf16x8 __attribute__((ext_vector_type(8)));
typedef unsigned short u16x4 __attribute__((ext_vector_type(4)));

__device__ __forceinline__ unsigned short f2b(float f) {
  __hip_bfloat16 h = __float2bfloat16(f);
  return *reinterpret_cast<unsigned short*>(&h);
}
__device__ __forceinline__ float b2f(unsigned short h) {
  union { unsigned u; float f; } v; v.u = ((unsigned)h) << 16;
  return v.f;
}
// cubic-tanh GELU; rcp approx instead of exact divide
__device__ __forceinline__ float gelu_fast(float y) {
  float u = y * (1.0f + 0.044715f * y * y);
  float e = __expf(1.5957691216057308f * u);     // e^{2*0.7978845608*u}
  float t = 1.0f - 2.0f * __builtin_amdgcn_rcpf(e + 1.0f);
  return 0.5f * y * (1.0f + t);
}
#define MFMA(a, b, c) __builtin_amdgcn_mfma_f32_16x16x32_bf16(a, b, c, 0, 0, 0)

// ---------------------------------------------------------------------------
// k_gram: EXACTLY 256 blocks. 64-row Gram partial via MFMA (8 waves), partG
// stored bf16 in MFMA C-fragment flat order:
//   fidx(w,tj,l,q) = (w*8+tj)*256 + l*4 + q  holding
//   G[ci=w*16+(l>>4)*4+q][cj=tj*16+(l&15)].
// Staging: f32x4 global loads, in-register f32 colsum partials, bf16 to LDS.
// Blocks 0-11 additionally pack W_w / phi_w into bf16 B-fragment order:
//   o = ((nt*KT+kt)*64 + lane)*8 + j  holds
//   B[k = kt*32 + (lane>>4)*8 + j][n = nt*16 + (lane&15)].
// ---------------------------------------------------------------------------
__global__ __launch_bounds__(512) void k_gram(
    const float* __restrict__ x, unsigned short* __restrict__ partG,
    float* __restrict__ partS,
    unsigned short* __restrict__ wtf, unsigned short* __restrict__ pwf,
    const float* __restrict__ W_w, const float* __restrict__ phi_w) {
  __shared__ short xsT[C * 76];     // [c][n] bf16, stride 76
  __shared__ float csp[16][C];      // colsum partials (16 row-groups)
  const int blk = blockIdx.x;
  const int tid = threadIdx.x;
  const int b = blk >> 7, chunk = blk & 127;
  const float* xb = x + ((size_t)(b * NB + chunk * 64)) * C;
  {
    // thread: c-quad = (tid&31)*4, rows n = it*16 + (tid>>5), it=0..3
    const int cq = (tid & 31) * 4, rg = tid >> 5;
    float cs0 = 0.f, cs1 = 0.f, cs2 = 0.f, cs3 = 0.f;
#pragma unroll
    for (int it = 0; it < 4; ++it) {
      int n = it * 16 + rg;
      f32x4 v = *(const f32x4*)(xb + (size_t)n * C + cq);
      cs0 += v[0]; cs1 += v[1]; cs2 += v[2]; cs3 += v[3];
      xsT[(cq + 0) * 76 + n] = (short)f2b(v[0]);
      xsT[(cq + 1) * 76 + n] = (short)f2b(v[1]);
      xsT[(cq + 2) * 76 + n] = (short)f2b(v[2]);
      xsT[(cq + 3) * 76 + n] = (short)f2b(v[3]);
    }
    csp[rg][cq + 0] = cs0;
    csp[rg][cq + 1] = cs1;
    csp[rg][cq + 2] = cs2;
    csp[rg][cq + 3] = cs3;
  }
  __syncthreads();
  const int l = tid & 63, w = tid >> 6;       // 8 waves, wave = 16-row G tile
  const int lr = l & 15, lq = l >> 4;
  f32x4 acc[8];
#pragma unroll
  for (int tj = 0; tj < 8; ++tj) acc[tj] = (f32x4)(0.f);
  bf16x8 af[2];
#pragma unroll
  for (int kk = 0; kk < 2; ++kk)
    af[kk] = *(const bf16x8*)(&xsT[(w * 16 + lr) * 76 + kk * 32 + lq * 8]);
#pragma unroll
  for (int tj = 0; tj < 8; ++tj)
#pragma unroll
    for (int kk = 0; kk < 2; ++kk) {
      bf16x8 bfr = *(const bf16x8*)(&xsT[(tj * 16 + lr) * 76 + kk * 32 + lq * 8]);
      acc[tj] = MFMA(af[kk], bfr, acc[tj]);
    }
  // store in fragment order: lane-contiguous u16x4 (8B) per tj
  unsigned short* dst = partG + (size_t)blk * (C * C);
#pragma unroll
  for (int tj = 0; tj < 8; ++tj) {
    u16x4 pv;
#pragma unroll
    for (int q = 0; q < 4; ++q) pv[q] = f2b(acc[tj][q]);
    *(u16x4*)(dst + (w * 8 + tj) * 256 + l * 4) = pv;
  }
  if (tid < C) {
    float s = 0.f;
#pragma unroll
    for (int g = 0; g < 16; ++g) s += csp[g][tid];
    partS[blk * C + tid] = s;
  }
  // ---- weight packing folded into blocks 0-11 (no extra block-wave) ----
  if (blk < 8) {        // wtf: 16384 elems, 2048/block
    int o0 = blk * 2048 + tid * 4;
    u16x4 v;
#pragma unroll
    for (int q = 0; q < 4; ++q) {
      int o = o0 + q;
      int j = o & 7, lane = (o >> 3) & 63, kt = (o >> 9) & 3, nt = o >> 11;
      int n = nt * 16 + (lane & 15);
      int k = kt * 32 + ((lane >> 4) << 3) + j;
      v[q] = f2b(W_w[k * C + n]);
    }
    *(u16x4*)(wtf + o0) = v;
  } else if (blk < 12) { // pwf: 8192 elems, 2048/block
    int o0 = (blk - 8) * 2048 + tid * 4;
    u16x4 v;
#pragma unroll
    for (int q = 0; q < 4; ++q) {
      int o = o0 + q;
      int j = o & 7, lane = (o >> 3) & 63, kt = (o >> 9) & 3, nt = o >> 11;
      int r = nt * 16 + (lane & 15);
      int c = kt * 32 + ((lane >> 4) << 3) + j;
      v[q] = f2b(phi_w[c * RANK + r]);
    }
    *(u16x4*)(pwf + o0) = v;
  }
}

// ---------------------------------------------------------------------------
// k_reduce: EXACTLY 256 blocks. b = e>>7, i0 = (e&127)*128; 256 thr =
// (chg 8) x (ig 32); each thread sums 16 chunks of u16x4; LDS tree.
// Blocks 0-1 additionally reduce partS for batch e (folded).
// ---------------------------------------------------------------------------
__global__ __launch_bounds__(256) void k_reduce(
    const unsigned short* __restrict__ partG, const float* __restrict__ partS,
    float* __restrict__ gsumG, float* __restrict__ gsumS) {
  __shared__ f32x4 red[256];
  __shared__ float s2[2][C];
  const int e = blockIdx.x, tid = threadIdx.x;
  const int b = e >> 7, i0 = (e & 127) * 128;
  const int chg = tid >> 5, ig = tid & 31;
  f32x4 a = (f32x4)(0.f);
  const unsigned short* base =
      partG + (size_t)(b * NCHUNK + chg * 16) * (C * C) + i0 + ig * 4;
#pragma unroll
  for (int cc = 0; cc < 16; ++cc) {
    u16x4 v = *(const u16x4*)(base + (size_t)cc * (C * C));
#pragma unroll
    for (int q = 0; q < 4; ++q) a[q] += b2f(v[q]);
  }
  red[tid] = a;
  if (e < 2) {  // partS reduce for batch e
    const int c = tid & 127, half = tid >> 7;
    const float* p = partS + (size_t)(e * NCHUNK + half * 64) * C + c;
    float s = 0.f;
#pragma unroll
    for (int cc = 0; cc < 64; ++cc) s += p[(size_t)cc * C];
    s2[half][c] = s;
  }
  __syncthreads();
  if (tid < 32) {
    f32x4 s = red[tid];
#pragma unroll
    for (int g = 1; g < 8; ++g) {
      f32x4 r = red[g * 32 + tid];
#pragma unroll
      for (int q = 0; q < 4; ++q) s[q] += r[q];
    }
    *(f32x4*)(&gsumG[b * (C * C) + i0 + tid * 4]) = s;
  }
  if (e < 2 && tid < C) gsumS[e * C + tid] = s2[0][tid] + s2[1][tid];
}

// ---------------------------------------------------------------------------
// k_integral: integ[b][r][c] = (sum_k psiw[k][r*C+c]*G[b][k][c]
//                               + psib[r*C+c]*S[b][c]) / NB -> itf (bf16 frag)
// grid (r=64, ch=4), 256 threads = kg(8) x c32(32); both batches per thread.
// G is in fragment-flat order: 4 consecutive k (one q-group) = one f32x4.
//   fidx(k4,c) = ((k4>>2)*8 + (c>>4))*256 + ((k4&3)*16 + (c&15))*4
// ---------------------------------------------------------------------------
__global__ __launch_bounds__(256) void k_integral(
    const float* __restrict__ psi_w, const float* __restrict__ psi_b,
    const float* __restrict__ gsumG, const float* __restrict__ gsumS,
    unsigned short* __restrict__ itf) {
  __shared__ float red[2][8][32];
  const int r = blockIdx.x, ch = blockIdx.y;
  const int tid = threadIdx.x, kg = tid >> 5, c32 = tid & 31;
  const int c = ch * 32 + c32;
  const int tj = c >> 4, lr = c & 15;
  const float* psW = psi_w + (size_t)r * C + c;
  float a0 = 0.f, a1 = 0.f;
#pragma unroll
  for (int i = 0; i < 4; ++i) {
    int k4 = kg * 4 + i;               // k = k4*4 + q, q=0..3
    int fidx = ((k4 >> 2) * 8 + tj) * 256 + ((k4 & 3) * 16 + lr) * 4;
    f32x4 g0 = *(const f32x4*)(gsumG + fidx);
    f32x4 g1 = *(const f32x4*)(gsumG + C * C + fidx);
#pragma unroll
    for (int q = 0; q < 4; ++q) {
      float pw = psW[(size_t)(k4 * 4 + q) * (RANK * C)];
      a0 += pw * g0[q];
      a1 += pw * g1[q];
    }
  }
  red[0][kg][c32] = a0;
  red[1][kg][c32] = a1;
  __syncthreads();
  if (tid < 64) {
    int b = tid >> 5, cc = tid & 31;
    float s = 0.f;
#pragma unroll
    for (int g = 0; g < 8; ++g) s += red[b][g][cc];
    int cg = ch * 32 + cc;
    s += psi_b[r * C + cg] * gsumS[b * C + cg];
    s *= (1.0f / NB);
    int nt = cg >> 4, kt = r >> 5;
    int lane = ((r >> 3) & 3) * 16 + (cg & 15), j = r & 7;
    itf[(size_t)(((b * 8 + nt) * 2 + kt) * 64 + lane) * 8 + j] = f2b(s);
  }
}

// ---------------------------------------------------------------------------
// k_main: 64 rows/block, 512 threads (8 waves = 2m x 4n), MFMA fused.
// Halved weight-fragment traffic vs 32-row blocks (256 blocks instead of
// 512 re-reading the same 80KB of fragments). A-fragments loaded directly
// from row-major f32 x, converted in-register; single barrier (phi exch).
//   T1 phi = x*phi_w + phi_b ; T2 acc = x*W_w + W_b ; T3 acc += phi*integ
//   out = gelu_fast(acc)
// ---------------------------------------------------------------------------
__global__ __launch_bounds__(512, 1) void k_main(
    const float* __restrict__ x, const float* __restrict__ W_b,
    const float* __restrict__ phi_b, const unsigned short* __restrict__ wtf,
    const unsigned short* __restrict__ pwf, const unsigned short* __restrict__ itf,
    float* __restrict__ out) {
  __shared__ short phT[64 * 72];
  const int tid = threadIdx.x, l = tid & 63, w = tid >> 6;
  const int wm = w >> 2, wn = w & 3;
  const int row0 = blockIdx.x * 64;
  const int b = blockIdx.x >> 7;
  const int lr = l & 15, lq = l >> 4;
  bf16x8 wb[2][4], pw[4], itb[2][2];
  const bf16x8* WF = (const bf16x8*)wtf;
  const bf16x8* PF = (const bf16x8*)pwf;
  const bf16x8* IF = (const bf16x8*)itf;
#pragma unroll
  for (int j = 0; j < 2; ++j)
#pragma unroll
    for (int kt = 0; kt < 4; ++kt)
      wb[j][kt] = WF[((wn * 2 + j) * 4 + kt) * 64 + l];
#pragma unroll
  for (int kt = 0; kt < 4; ++kt) pw[kt] = PF[(wn * 4 + kt) * 64 + l];
#pragma unroll
  for (int j = 0; j < 2; ++j)
#pragma unroll
    for (int kt = 0; kt < 2; ++kt)
      itb[j][kt] = IF[((b * 8 + wn * 2 + j) * 2 + kt) * 64 + l];
  // A-fragments straight from global x (f32 -> bf16 in-register)
  bf16x8 afr[2][4];
#pragma unroll
  for (int h = 0; h < 2; ++h) {
    const float* xr = x + (size_t)(row0 + wm * 32 + h * 16 + lr) * C + lq * 8;
#pragma unroll
    for (int kt = 0; kt < 4; ++kt) {
      f32x4 v0 = *(const f32x4*)(xr + kt * 32);
      f32x4 v1 = *(const f32x4*)(xr + kt * 32 + 4);
      bf16x8 pv;
#pragma unroll
      for (int q = 0; q < 4; ++q) {
        pv[q] = (short)f2b(v0[q]);
        pv[q + 4] = (short)f2b(v1[q]);
      }
      afr[h][kt] = pv;
    }
  }
  float wb0 = W_b[wn * 32 + lr], wb1 = W_b[wn * 32 + 16 + lr];
  float pb0 = phi_b[wn * 16 + lr];
  f32x4 acc[2][2], pacc[2];
#pragma unroll
  for (int i = 0; i < 2; ++i) {
    acc[i][0] = (f32x4)(wb0);
    acc[i][1] = (f32x4)(wb1);
    pacc[i] = (f32x4)(pb0);
  }
#pragma unroll
  for (int kt = 0; kt < 4; ++kt) {
    pacc[0] = MFMA(afr[0][kt], pw[kt], pacc[0]);
    pacc[1] = MFMA(afr[1][kt], pw[kt], pacc[1]);
    acc[0][0] = MFMA(afr[0][kt], wb[0][kt], acc[0][0]);
    acc[0][1] = MFMA(afr[0][kt], wb[1][kt], acc[0][1]);
    acc[1][0] = MFMA(afr[1][kt], wb[0][kt], acc[1][0]);
    acc[1][1] = MFMA(afr[1][kt], wb[1][kt], acc[1][1]);
  }
#pragma unroll
  for (int i = 0; i < 2; ++i)
#pragma unroll
    for (int q = 0; q < 4; ++q) {
      int row = wm * 32 + i * 16 + lq * 4 + q;
      phT[row * 72 + wn * 16 + lr] = (short)f2b(pacc[i][q]);
    }
  __syncthreads();
#pragma unroll
  for (int kt = 0; kt < 2; ++kt) {
    bf16x8 p0 = *(const bf16x8*)(&phT[(wm * 32 + lr) * 72 + kt * 32 + lq * 8]);
    bf16x8 p1 =
        *(const bf16x8*)(&phT[(wm * 32 + 16 + lr) * 72 + kt * 32 + lq * 8]);
    acc[0][0] = MFMA(p0, itb[0][kt], acc[0][0]);
    acc[0][1] = MFMA(p0, itb[1][kt], acc[0][1]);
    acc[1][0] = MFMA(p1, itb[0][kt], acc[1][0]);
    acc[1][1] = MFMA(p1, itb[1][kt], acc[1][1]);
  }
#pragma unroll
  for (int i = 0; i < 2; ++i)
#pragma unroll
    for (int j = 0; j < 2; ++j)
#pragma unroll
      for (int q = 0; q < 4; ++q) {
        int row = row0 + wm * 32 + i * 16 + lq * 4 + q;
        int col = wn * 32 + j * 16 + lr;
        out[(size_t)row * C + col] = gelu_fast(acc[i][j][q]);
      }
}

extern "C" void kernel_launch(void* const* d_in, const int* in_sizes, int n_in,
                              void* d_out, int out_size, void* d_ws, size_t ws_size,
                              hipStream_t stream) {
  const float* x     = (const float*)d_in[0];
  const float* W_w   = (const float*)d_in[1];
  const float* W_b   = (const float*)d_in[2];
  const float* phi_w = (const float*)d_in[3];
  const float* phi_b = (const float*)d_in[4];
  const float* psi_w = (const float*)d_in[5];
  const float* psi_b = (const float*)d_in[6];
  float* out = (float*)d_out;

  // ws: partG[256*16384 bf16] | partS[256*128 f32] | gsumG[2*16384 f32]
  //     | gsumS[256 f32] | wtf[16384 bf16] | pwf[8192 bf16] | itf[16384 bf16]
  unsigned short* partG = (unsigned short*)d_ws;
  float* partS = (float*)(partG + (size_t)BATCH * NCHUNK * C * C);
  float* gsumG = partS + (size_t)BATCH * NCHUNK * C;
  float* gsumS = gsumG + BATCH * C * C;
  unsigned short* wtf = (unsigned short*)(gsumS + BATCH * C);
  unsigned short* pwf = wtf + 16384;
  unsigned short* itf = pwf + 8192;

  k_gram<<<BATCH * NCHUNK, 512, 0, stream>>>(x, partG, partS, wtf, pwf,
                                             W_w, phi_w);
  k_reduce<<<BATCH * NCHUNK, 256, 0, stream>>>(partG, partS, gsumG, gsumS);
  k_integral<<<dim3(RANK, 4), 256, 0, stream>>>(psi_w, psi_b, gsumG, gsumS,
                                                itf);
  k_main<<<(BATCH * NB) / 64, 512, 0, stream>>>(x, W_b, phi_b, wtf, pwf, itf,
                                                out);
}

// Round 13
// 26.354 us; speedup vs baseline: 1.0456x; 1.0392x over previous
//
#include <hip/hip_runtime.h>
#include <hip/hip_bf16.h>
#include <math.h>

#define C 128
#define RANK 64
#define NB 8192
#define BATCH 2
#define NCHUNK 128                 // 64-row chunks per batch

typedef float f32x4 __attribute__((ext_vector_type(4)));
typedef short bf16x8 __attribute__((ext_vector_type(8)));
typedef unsigned short u16x4 __attribute__((ext_vector_type(4)));

__device__ __forceinline__ unsigned short f2b(float f) {
  __hip_bfloat16 h = __float2bfloat16(f);
  return *reinterpret_cast<unsigned short*>(&h);
}
__device__ __forceinline__ float b2f(unsigned short h) {
  union { unsigned u; float f; } v; v.u = ((unsigned)h) << 16;
  return v.f;
}
// cubic-tanh GELU; rcp approx (1 ULP) instead of exact divide
__device__ __forceinline__ float gelu_fast(float y) {
  float u = y * (1.0f + 0.044715f * y * y);
  float e = __expf(1.5957691216057308f * u);     // e^{2*0.7978845608*u}
  float t = 1.0f - 2.0f * __builtin_amdgcn_rcpf(e + 1.0f);
  return 0.5f * y * (1.0f + t);
}
#define MFMA(a, b, c) __builtin_amdgcn_mfma_f32_16x16x32_bf16(a, b, c, 0, 0, 0)

// ---------------------------------------------------------------------------
// k_gram: blocks [0,256): 64-row Gram partial via MFMA (8 waves), stored as
// bf16 in MFMA C-FRAGMENT FLAT ORDER: fidx(w,tj,l,q) = (w*8+tj)*256 + l*4 + q
// holding G[ci=w*16+(l>>4)*4+q][cj=tj*16+(l&15)]. Lane-contiguous u16x4
// stores = perfect coalescing. f32 column-sum partial unchanged.
// Blocks [256,268): pack W_w / phi_w into bf16 MFMA B-fragment order:
//   o = ((nt*KT+kt)*64 + lane)*8 + j  holds
//   B[k = kt*32 + (lane>>4)*8 + j][n = nt*16 + (lane&15)].
// ---------------------------------------------------------------------------
__global__ __launch_bounds__(512) void k_gram(
    const float* __restrict__ x, unsigned short* __restrict__ partG,
    float* __restrict__ partS,
    unsigned short* __restrict__ wtf, unsigned short* __restrict__ pwf,
    const float* __restrict__ W_w, const float* __restrict__ phi_w) {
  const int blk = blockIdx.x;
  const int tid = threadIdx.x;
  if (blk >= BATCH * NCHUNK) {
    const int p = blk - BATCH * NCHUNK;
    if (p < 8) {   // W_w -> wtf, 16384 elems
      int o0 = p * 2048 + tid * 4;
      u16x4 v;
#pragma unroll
      for (int q = 0; q < 4; ++q) {
        int o = o0 + q;
        int j = o & 7, lane = (o >> 3) & 63, kt = (o >> 9) & 3, nt = o >> 11;
        int n = nt * 16 + (lane & 15);
        int k = kt * 32 + ((lane >> 4) << 3) + j;
        v[q] = f2b(W_w[k * C + n]);
      }
      *(u16x4*)(wtf + o0) = v;
    } else {       // phi_w -> pwf, 8192 elems
      int o0 = (p - 8) * 2048 + tid * 4;
      u16x4 v;
#pragma unroll
      for (int q = 0; q < 4; ++q) {
        int o = o0 + q;
        int j = o & 7, lane = (o >> 3) & 63, kt = (o >> 9) & 3, nt = o >> 11;
        int r = nt * 16 + (lane & 15);
        int c = kt * 32 + ((lane >> 4) << 3) + j;
        v[q] = f2b(phi_w[c * RANK + r]);
      }
      *(u16x4*)(pwf + o0) = v;
    }
    return;
  }
  __shared__ short xsT[C * 76];     // [c][n], stride 76: aligned + conflict-free
  __shared__ float csp[4][C];
  const int b = blk >> 7, chunk = blk & 127;
  const float* xb = x + ((size_t)(b * NB + chunk * 64)) * C;
  {
    const int c = tid & 127, ng = tid >> 7;   // ng 0..3
    float cs = 0.f;
#pragma unroll
    for (int it = 0; it < 4; ++it) {
      int n0 = it * 16 + ng * 4;
      u16x4 pv;
#pragma unroll
      for (int q = 0; q < 4; ++q) {
        float v = xb[(size_t)(n0 + q) * C + c];
        cs += v;
        pv[q] = f2b(v);
      }
      *(u16x4*)(&xsT[c * 76 + n0]) = pv;
    }
    csp[ng][c] = cs;
  }
  __syncthreads();
  const int l = tid & 63, w = tid >> 6;       // 8 waves, wave = 16-row G tile
  const int lr = l & 15, lq = l >> 4;
  f32x4 acc[8];
#pragma unroll
  for (int tj = 0; tj < 8; ++tj) acc[tj] = (f32x4)(0.f);
  bf16x8 af[2];
#pragma unroll
  for (int kk = 0; kk < 2; ++kk)
    af[kk] = *(const bf16x8*)(&xsT[(w * 16 + lr) * 76 + kk * 32 + lq * 8]);
#pragma unroll
  for (int tj = 0; tj < 8; ++tj)
#pragma unroll
    for (int kk = 0; kk < 2; ++kk) {
      bf16x8 bfr = *(const bf16x8*)(&xsT[(tj * 16 + lr) * 76 + kk * 32 + lq * 8]);
      acc[tj] = MFMA(af[kk], bfr, acc[tj]);
    }
  // store in fragment order: lane-contiguous u16x4 (8B) per tj
  unsigned short* dst = partG + (size_t)blk * (C * C);
#pragma unroll
  for (int tj = 0; tj < 8; ++tj) {
    u16x4 pv;
#pragma unroll
    for (int q = 0; q < 4; ++q) pv[q] = f2b(acc[tj][q]);
    *(u16x4*)(dst + (w * 8 + tj) * 256 + l * 4) = pv;
  }
  if (tid < C)
    partS[blk * C + tid] = csp[0][tid] + csp[1][tid] + csp[2][tid] + csp[3][tid];
}

// ---------------------------------------------------------------------------
// k_reduce: chunk-parallel, layout-agnostic elementwise sum.
// Blocks [0,256): b = e>>7, i0 = (e&127)*128; 256 thr = (chg 8) x (ig 32);
// each thread sums 16 chunks of u16x4; LDS tree. Blocks [256,258): partS.
// ---------------------------------------------------------------------------
__global__ __launch_bounds__(256) void k_reduce(
    const unsigned short* __restrict__ partG, const float* __restrict__ partS,
    float* __restrict__ gsumG, float* __restrict__ gsumS) {
  const int e = blockIdx.x, tid = threadIdx.x;
  if (e < 256) {
    __shared__ f32x4 red[256];
    const int b = e >> 7, i0 = (e & 127) * 128;
    const int chg = tid >> 5, ig = tid & 31;
    f32x4 a = (f32x4)(0.f);
    const unsigned short* base =
        partG + (size_t)(b * NCHUNK + chg * 16) * (C * C) + i0 + ig * 4;
#pragma unroll
    for (int cc = 0; cc < 16; ++cc) {
      u16x4 v = *(const u16x4*)(base + (size_t)cc * (C * C));
#pragma unroll
      for (int q = 0; q < 4; ++q) a[q] += b2f(v[q]);
    }
    red[tid] = a;
    __syncthreads();
    if (tid < 32) {
      f32x4 s = red[tid];
#pragma unroll
      for (int g = 1; g < 8; ++g) {
        f32x4 r = red[g * 32 + tid];
#pragma unroll
        for (int q = 0; q < 4; ++q) s[q] += r[q];
      }
      *(f32x4*)(&gsumG[b * (C * C) + i0 + tid * 4]) = s;
    }
  } else {
    __shared__ float s2[2][C];
    const int b = e - 256;
    const int c = tid & 127, half = tid >> 7;
    const float* p = partS + (size_t)(b * NCHUNK + half * 64) * C + c;
    float s = 0.f;
#pragma unroll
    for (int cc = 0; cc < 64; ++cc) s += p[(size_t)cc * C];
    s2[half][c] = s;
    __syncthreads();
    if (tid < C) gsumS[b * C + tid] = s2[0][tid] + s2[1][tid];
  }
}

// ---------------------------------------------------------------------------
// k_integral: integ[b][r][c] = (sum_k psiw[k][r*C+c]*G[b][k][c]
//                               + psib[r*C+c]*S[b][c]) / NB -> itf (bf16 frag)
// grid (r=64, ch=4), 256 threads = kg(8) x c32(32); both batches per thread.
// G is in fragment-flat order: 4 consecutive k (one q-group) = one f32x4.
//   fidx(k4,c) = ((k4>>2)*8 + (c>>4))*256 + ((k4&3)*16 + (c&15))*4
// ---------------------------------------------------------------------------
__global__ __launch_bounds__(256) void k_integral(
    const float* __restrict__ psi_w, const float* __restrict__ psi_b,
    const float* __restrict__ gsumG, const float* __restrict__ gsumS,
    unsigned short* __restrict__ itf) {
  __shared__ float red[2][8][32];
  const int r = blockIdx.x, ch = blockIdx.y;
  const int tid = threadIdx.x, kg = tid >> 5, c32 = tid & 31;
  const int c = ch * 32 + c32;
  const int tj = c >> 4, lr = c & 15;
  const float* psW = psi_w + (size_t)r * C + c;
  float a0 = 0.f, a1 = 0.f;
#pragma unroll
  for (int i = 0; i < 4; ++i) {
    int k4 = kg * 4 + i;               // k = k4*4 + q, q=0..3
    int fidx = ((k4 >> 2) * 8 + tj) * 256 + ((k4 & 3) * 16 + lr) * 4;
    f32x4 g0 = *(const f32x4*)(gsumG + fidx);
    f32x4 g1 = *(const f32x4*)(gsumG + C * C + fidx);
#pragma unroll
    for (int q = 0; q < 4; ++q) {
      float pw = psW[(size_t)(k4 * 4 + q) * (RANK * C)];
      a0 += pw * g0[q];
      a1 += pw * g1[q];
    }
  }
  red[0][kg][c32] = a0;
  red[1][kg][c32] = a1;
  __syncthreads();
  if (tid < 64) {
    int b = tid >> 5, cc = tid & 31;
    float s = 0.f;
#pragma unroll
    for (int g = 0; g < 8; ++g) s += red[b][g][cc];
    int cg = ch * 32 + cc;
    s += psi_b[r * C + cg] * gsumS[b * C + cg];
    s *= (1.0f / NB);
    int nt = cg >> 4, kt = r >> 5;
    int lane = ((r >> 3) & 3) * 16 + (cg & 15), j = r & 7;
    itf[(size_t)(((b * 8 + nt) * 2 + kt) * 64 + lane) * 8 + j] = f2b(s);
  }
}

// ---------------------------------------------------------------------------
// k_main: 32 rows/block, 256 threads (4 waves = 4 col-tiles), MFMA fused.
// A-fragments loaded directly from row-major f32 x (L3-warm), converted
// in-register; single barrier (phi exchange).
//   T1 phi = x*phi_w + phi_b ; T2 acc = x*W_w + W_b ; T3 acc += phi*integ
//   out = gelu_fast(acc)
// ---------------------------------------------------------------------------
__global__ __launch_bounds__(256, 2) void k_main(
    const float* __restrict__ x, const float* __restrict__ W_b,
    const float* __restrict__ phi_b, const unsigned short* __restrict__ wtf,
    const unsigned short* __restrict__ pwf, const unsigned short* __restrict__ itf,
    float* __restrict__ out) {
  __shared__ short phT[32 * 72];
  const int tid = threadIdx.x, l = tid & 63, wn = tid >> 6;
  const int row0 = blockIdx.x * 32;
  const int b = blockIdx.x >> 8;
  const int lr = l & 15, lq = l >> 4;
  bf16x8 wb[2][4], pw[4], itb[2][2];
  const bf16x8* WF = (const bf16x8*)wtf;
  const bf16x8* PF = (const bf16x8*)pwf;
  const bf16x8* IF = (const bf16x8*)itf;
#pragma unroll
  for (int j = 0; j < 2; ++j)
#pragma unroll
    for (int kt = 0; kt < 4; ++kt)
      wb[j][kt] = WF[((wn * 2 + j) * 4 + kt) * 64 + l];
#pragma unroll
  for (int kt = 0; kt < 4; ++kt) pw[kt] = PF[(wn * 4 + kt) * 64 + l];
#pragma unroll
  for (int j = 0; j < 2; ++j)
#pragma unroll
    for (int kt = 0; kt < 2; ++kt)
      itb[j][kt] = IF[((b * 8 + wn * 2 + j) * 2 + kt) * 64 + l];
  bf16x8 afr[2][4];
#pragma unroll
  for (int h = 0; h < 2; ++h) {
    const float* xr = x + (size_t)(row0 + h * 16 + lr) * C + lq * 8;
#pragma unroll
    for (int kt = 0; kt < 4; ++kt) {
      f32x4 v0 = *(const f32x4*)(xr + kt * 32);
      f32x4 v1 = *(const f32x4*)(xr + kt * 32 + 4);
      bf16x8 pv;
#pragma unroll
      for (int q = 0; q < 4; ++q) {
        pv[q] = (short)f2b(v0[q]);
        pv[q + 4] = (short)f2b(v1[q]);
      }
      afr[h][kt] = pv;
    }
  }
  float wb0 = W_b[wn * 32 + lr], wb1 = W_b[wn * 32 + 16 + lr];
  float pb0 = phi_b[wn * 16 + lr];
  f32x4 acc[2][2], pacc[2];
#pragma unroll
  for (int i = 0; i < 2; ++i) {
    acc[i][0] = (f32x4)(wb0);
    acc[i][1] = (f32x4)(wb1);
    pacc[i] = (f32x4)(pb0);
  }
#pragma unroll
  for (int kt = 0; kt < 4; ++kt) {
    pacc[0] = MFMA(afr[0][kt], pw[kt], pacc[0]);
    pacc[1] = MFMA(afr[1][kt], pw[kt], pacc[1]);
    acc[0][0] = MFMA(afr[0][kt], wb[0][kt], acc[0][0]);
    acc[0][1] = MFMA(afr[0][kt], wb[1][kt], acc[0][1]);
    acc[1][0] = MFMA(afr[1][kt], wb[0][kt], acc[1][0]);
    acc[1][1] = MFMA(afr[1][kt], wb[1][kt], acc[1][1]);
  }
#pragma unroll
  for (int i = 0; i < 2; ++i)
#pragma unroll
    for (int q = 0; q < 4; ++q) {
      int row = i * 16 + lq * 4 + q;
      phT[row * 72 + wn * 16 + lr] = (short)f2b(pacc[i][q]);
    }
  __syncthreads();
#pragma unroll
  for (int kt = 0; kt < 2; ++kt) {
    bf16x8 p0 = *(const bf16x8*)(&phT[lr * 72 + kt * 32 + lq * 8]);
    bf16x8 p1 = *(const bf16x8*)(&phT[(16 + lr) * 72 + kt * 32 + lq * 8]);
    acc[0][0] = MFMA(p0, itb[0][kt], acc[0][0]);
    acc[0][1] = MFMA(p0, itb[1][kt], acc[0][1]);
    acc[1][0] = MFMA(p1, itb[0][kt], acc[1][0]);
    acc[1][1] = MFMA(p1, itb[1][kt], acc[1][1]);
  }
#pragma unroll
  for (int i = 0; i < 2; ++i)
#pragma unroll
    for (int j = 0; j < 2; ++j)
#pragma unroll
      for (int q = 0; q < 4; ++q) {
        int row = row0 + i * 16 + lq * 4 + q;
        int col = wn * 32 + j * 16 + lr;
        out[(size_t)row * C + col] = gelu_fast(acc[i][j][q]);
      }
}

extern "C" void kernel_launch(void* const* d_in, const int* in_sizes, int n_in,
                              void* d_out, int out_size, void* d_ws, size_t ws_size,
                              hipStream_t stream) {
  const float* x     = (const float*)d_in[0];
  const float* W_w   = (const float*)d_in[1];
  const float* W_b   = (const float*)d_in[2];
  const float* phi_w = (const float*)d_in[3];
  const float* phi_b = (const float*)d_in[4];
  const float* psi_w = (const float*)d_in[5];
  const float* psi_b = (const float*)d_in[6];
  float* out = (float*)d_out;

  // ws: partG[256*16384 bf16] | partS[256*128 f32] | gsumG[2*16384 f32]
  //     | gsumS[256 f32] | wtf[16384 bf16] | pwf[8192 bf16] | itf[16384 bf16]
  unsigned short* partG = (unsigned short*)d_ws;
  float* partS = (float*)(partG + (size_t)BATCH * NCHUNK * C * C);
  float* gsumG = partS + (size_t)BATCH * NCHUNK * C;
  float* gsumS = gsumG + BATCH * C * C;
  unsigned short* wtf = (unsigned short*)(gsumS + BATCH * C);
  unsigned short* pwf = wtf + 16384;
  unsigned short* itf = pwf + 8192;

  k_gram<<<BATCH * NCHUNK + 12, 512, 0, stream>>>(x, partG, partS, wtf, pwf,
                                                  W_w, phi_w);
  k_reduce<<<258, 256, 0, stream>>>(partG, partS, gsumG, gsumS);
  k_integral<<<dim3(RANK, 4), 256, 0, stream>>>(psi_w, psi_b, gsumG, gsumS,
                                                itf);
  k_main<<<(BATCH * NB) / 32, 256, 0, stream>>>(x, W_b, phi_b, wtf, pwf, itf,
                                                out);
}